// Round 7
// baseline (18087.714 us; speedup 1.0000x reference)
//
#include <hip/hip_runtime.h>

// NSAFlowLayer: B=32 flows of (P=16384, K=64), 50 iters:
//   Y' = 0.9Y+0.1X0 ; S = NS_invsqrt(Y'^T Y') ; Y = relu(Y' @ (I+S)/2)
// R6 -> R7: (1) k_ns folded into k_fused tail blocks (per-batch atomic
// counter; last block runs NS inline in union'd LDS, emits S2=(I+S)/2 for the
// next dispatch) -> the 68us/iter k_ns dispatch is gone. (2) S2 symmetric,
// B-frags in REGISTERS (no sS LDS, no ypv conflicted reads, no blend VALU).
// (3) Zt staging vectorized to b64; partials stored transposed (G symmetric,
// coalesced f4). LDS 52.3KB union -> 3 blocks/CU (same 12 waves/CU as R6).

#define BATCH 32
#define NP    16384
#define NK    64
#define NITER 50
#define NSIT  8
#define EPSC  1e-8f
#define CH    64
#define NT    256
#define SP    68               // f32 LDS stride (NS mats)
#define SPH   72               // f16 LDS stride (Zt staging)

using h4    = __attribute__((ext_vector_type(4))) _Float16;
using h8    = __attribute__((ext_vector_type(8))) _Float16;
using f32x4 = __attribute__((ext_vector_type(4))) float;

#define MFMA16x32(A, B, C) __builtin_amdgcn_mfma_f32_16x16x32_f16(A, B, C, 0, 0, 0)

#define FMA16(D, A0, A1, A2, A3, BV) do {                                  \
  D[0][0] = fmaf(A0, BV.x, D[0][0]); D[0][1] = fmaf(A0, BV.y, D[0][1]);    \
  D[0][2] = fmaf(A0, BV.z, D[0][2]); D[0][3] = fmaf(A0, BV.w, D[0][3]);    \
  D[1][0] = fmaf(A1, BV.x, D[1][0]); D[1][1] = fmaf(A1, BV.y, D[1][1]);    \
  D[1][2] = fmaf(A1, BV.z, D[1][2]); D[1][3] = fmaf(A1, BV.w, D[1][3]);    \
  D[2][0] = fmaf(A2, BV.x, D[2][0]); D[2][1] = fmaf(A2, BV.y, D[2][1]);    \
  D[2][2] = fmaf(A2, BV.z, D[2][2]); D[2][3] = fmaf(A2, BV.w, D[2][3]);    \
  D[3][0] = fmaf(A3, BV.x, D[3][0]); D[3][1] = fmaf(A3, BV.y, D[3][1]);    \
  D[3][2] = fmaf(A3, BV.z, D[3][2]); D[3][3] = fmaf(A3, BV.w, D[3][3]);    \
} while (0)

// LDS union: k_fused main phase uses zt (18.4 KB); NS phase uses ns (52.2 KB)
union SMemF {
  struct { _Float16 a[CH][SPH]; _Float16 b[CH][SPH]; } zt;
  struct { float Y[NK][SP]; float Z[NK][SP]; float T[NK][SP];
           float red[16]; int tail; } ns;
};

// ---------------------------------------------------------------------------
// ns_compute: M = sum of npart partial grams; 8 coupled NS iters (iter-0
// Z=I shortcut); emit S2 = (I + Z/sqrt(nrm))/2 as f16 hi/lo (row-major,
// symmetric). 256 threads, 4x4 tiles. Caller provides union'd LDS.
// ---------------------------------------------------------------------------
__device__ void ns_compute(SMemF& sm, const float* __restrict__ pb, int npart,
                           _Float16* __restrict__ S2h,
                           _Float16* __restrict__ S2l, int tid) {
  float (*sA)[SP] = sm.ns.Y;
  float (*sB)[SP] = sm.ns.Z;
  float (*sT)[SP] = sm.ns.T;
  const int it = tid >> 4, jt = tid & 15;
  const int i0 = it * 4, j0 = jt * 4;

  float m[4][4] = {{0.f}};
  for (int p = 0; p < npart; ++p) {
    const float* pp = pb + (size_t)p * NK * NK;
#pragma unroll
    for (int a = 0; a < 4; ++a) {
      float4 v = *(const float4*)(pp + (i0 + a) * NK + j0);
      m[a][0] += v.x; m[a][1] += v.y; m[a][2] += v.z; m[a][3] += v.w;
    }
  }
  if (it == jt) sm.ns.red[it] = m[0][0] + m[1][1] + m[2][2] + m[3][3];
  __syncthreads();
  float nrm = EPSC;
#pragma unroll
  for (int i = 0; i < 16; ++i) nrm += sm.ns.red[i];
  const float inv = 1.0f / nrm;

#pragma unroll
  for (int a = 0; a < 4; ++a)
#pragma unroll
    for (int c = 0; c < 4; ++c)
      sA[i0 + a][j0 + c] = m[a][c] * inv;
  __syncthreads();

  // --- NS iter 0 (Z=I): T = 1.5I - 0.5Y ; Ynew = Y@T ; Z = T ---
  {
    float t[4][4];
#pragma unroll
    for (int a = 0; a < 4; ++a)
#pragma unroll
      for (int c = 0; c < 4; ++c) {
        t[a][c] = (((i0 + a) == (j0 + c)) ? 1.5f : 0.0f) -
                  0.5f * sA[i0 + a][j0 + c];
        sT[i0 + a][j0 + c] = t[a][c];
      }
    __syncthreads();
    float r1[4][4] = {{0.f}};
#pragma unroll 8
    for (int k = 0; k < NK; ++k) {
      float y0 = sA[i0 + 0][k], y1 = sA[i0 + 1][k];
      float y2 = sA[i0 + 2][k], y3 = sA[i0 + 3][k];
      float4 tv = *(const float4*)&sT[k][j0];
      FMA16(r1, y0, y1, y2, y3, tv);
    }
    __syncthreads();
#pragma unroll
    for (int a = 0; a < 4; ++a)
#pragma unroll
      for (int c = 0; c < 4; ++c) {
        sA[i0 + a][j0 + c] = r1[a][c];
        sB[i0 + a][j0 + c] = t[a][c];
      }
    __syncthreads();
  }

  // --- NS iters 1..7 ---
  for (int ns = 1; ns < NSIT; ++ns) {
    float d[4][4] = {{0.f}};
#pragma unroll 8
    for (int k = 0; k < NK; ++k) {
      float b0 = sB[i0 + 0][k], b1 = sB[i0 + 1][k];
      float b2 = sB[i0 + 2][k], b3 = sB[i0 + 3][k];
      float4 av = *(const float4*)&sA[k][j0];
      FMA16(d, b0, b1, b2, b3, av);
    }
#pragma unroll
    for (int a = 0; a < 4; ++a)
#pragma unroll
      for (int c = 0; c < 4; ++c)
        sT[i0 + a][j0 + c] =
            (((i0 + a) == (j0 + c)) ? 1.5f : 0.0f) - 0.5f * d[a][c];
    __syncthreads();

    float r1[4][4] = {{0.f}}, r2[4][4] = {{0.f}};
#pragma unroll 8
    for (int k = 0; k < NK; ++k) {
      float y0 = sA[i0 + 0][k], y1 = sA[i0 + 1][k];
      float y2 = sA[i0 + 2][k], y3 = sA[i0 + 3][k];
      float4 tv = *(const float4*)&sT[k][j0];
      FMA16(r1, y0, y1, y2, y3, tv);
      float t0 = sT[i0 + 0][k], t1 = sT[i0 + 1][k];
      float t2 = sT[i0 + 2][k], t3 = sT[i0 + 3][k];
      float4 zv = *(const float4*)&sB[k][j0];
      FMA16(r2, t0, t1, t2, t3, zv);
    }
    __syncthreads();
#pragma unroll
    for (int a = 0; a < 4; ++a)
#pragma unroll
      for (int c = 0; c < 4; ++c) {
        sA[i0 + a][j0 + c] = r1[a][c];
        sB[i0 + a][j0 + c] = r2[a][c];
      }
    __syncthreads();
  }

  // emit S2 = 0.5I + 0.5*sc*Z as f16 hi/lo (lo scaled by 2048)
  const float sc = 0.5f / sqrtf(nrm);
#pragma unroll
  for (int a = 0; a < 4; ++a)
#pragma unroll
    for (int c = 0; c < 4; ++c) {
      float s = sB[i0 + a][j0 + c] * sc +
                (((i0 + a) == (j0 + c)) ? 0.5f : 0.0f);
      _Float16 hh = (_Float16)s;
      S2h[(i0 + a) * NK + (j0 + c)] = hh;
      S2l[(i0 + a) * NK + (j0 + c)] = (_Float16)((s - (float)hh) * 2048.f);
    }
}

// ---------------------------------------------------------------------------
// k_init: Y := X0 ; gram partials of Y'_0 (= X0) ; zero counters.
// ---------------------------------------------------------------------------
__global__ __launch_bounds__(NT, 4) void k_init(const float* __restrict__ X0,
                                                float* __restrict__ Y,
                                                float* __restrict__ partials,
                                                unsigned* __restrict__ cnt,
                                                int shift) {
  __shared__ float sZ[CH][SP];
  const int tid = threadIdx.x, blk = blockIdx.x;
  if (blk == 0 && tid < BATCH) cnt[tid] = 0u;
  const int bpb = 1 << shift;
  const int b = blk >> shift, rb = blk & (bpb - 1);
  const int rpb = NP >> shift, nch = rpb / CH;
  const size_t base = ((size_t)b * NP + (size_t)rb * rpb) * NK;
  const float* __restrict__ x0 = X0 + base;
  float* __restrict__ y = Y + base;
  const int it = tid >> 4, jt = tid & 15;
  const int i0 = it * 4, j0 = jt * 4;
  float acc[4][4] = {{0.f}};

  for (int ch = 0; ch < nch; ++ch) {
    const float* xo = x0 + ch * CH * NK;
    float* yo = y + ch * CH * NK;
#pragma unroll
    for (int q = 0; q < 4; ++q) {
      int fi = (q * NT + tid) * 4;
      float4 xv = *(const float4*)(xo + fi);
      *(float4*)(yo + fi) = xv;
      int r = fi >> 6, c = fi & 63;
      *(float4*)&sZ[r][c] = xv;
    }
    __syncthreads();
#pragma unroll 8
    for (int r = 0; r < CH; ++r) {
      float4 zi = *(const float4*)&sZ[r][i0];
      float4 zj = *(const float4*)&sZ[r][j0];
      FMA16(acc, zi.x, zi.y, zi.z, zi.w, zj);
    }
    __syncthreads();
  }
  float* p = partials + (size_t)blk * NK * NK;
#pragma unroll
  for (int a = 0; a < 4; ++a)
    *(float4*)(p + (i0 + a) * NK + j0) =
        make_float4(acc[a][0], acc[a][1], acc[a][2], acc[a][3]);
}

// ---------------------------------------------------------------------------
// k_ns_once: standalone NS (only for iteration 0's S2).
// ---------------------------------------------------------------------------
__global__ __launch_bounds__(NT, 3) void k_ns_once(
    const float* __restrict__ partials, _Float16* __restrict__ S2h,
    _Float16* __restrict__ S2l, int bpb) {
  __shared__ SMemF sm;
  const int b = blockIdx.x;
  ns_compute(sm, partials + (size_t)b * bpb * NK * NK, bpb,
             S2h + (size_t)b * NK * NK, S2l + (size_t)b * NK * NK,
             threadIdx.x);
}

// ---------------------------------------------------------------------------
// k_fused: Ynew = relu(Y' @ S2), Y' = 0.9Y+0.1X0 ; write Y.
// If !last: Zt = (0.9Ynew+0.1X0)^T staged f16 hi/lo, gram via MFMA, partials
// stored (transposed f4, G symmetric); last block per batch runs NS inline.
// ---------------------------------------------------------------------------
__global__ __launch_bounds__(NT, 3) void k_fused(
    const float* __restrict__ X0, float* __restrict__ Y,
    const _Float16* __restrict__ S2h, const _Float16* __restrict__ S2l,
    float* __restrict__ partials, unsigned* __restrict__ cnt,
    int last, int shift) {
  __shared__ SMemF sm;

  const int tid = threadIdx.x, blk = blockIdx.x;
  const int bpb = 1 << shift;
  const int b = blk >> shift, rb = blk & (bpb - 1);
  const int rpb = NP >> shift, nch = rpb / CH;
  const size_t base = ((size_t)b * NP + (size_t)rb * rpb) * NK;
  const float* __restrict__ x0 = X0 + base;
  float* __restrict__ y = Y + base;

  const int wv = tid >> 6, ln = tid & 63;
  const int lr = ln & 15, lq = ln >> 4;

  // S2 B-fragments in registers (S2 symmetric -> row reads), L2-hot
  h8 sb_h[4][2], sb_l[4][2];
  {
    const _Float16* s2h = S2h + (size_t)b * NK * NK;
    const _Float16* s2l = S2l + (size_t)b * NK * NK;
#pragma unroll
    for (int tc = 0; tc < 4; ++tc)
#pragma unroll
      for (int kh = 0; kh < 2; ++kh) {
        int off = (16 * tc + lr) * NK + 32 * kh + 8 * lq;
        sb_h[tc][kh] = *(const h8*)(s2h + off);
        sb_l[tc][kh] = *(const h8*)(s2l + off);
      }
  }

  f32x4 gacc[4], glo[4];
#pragma unroll
  for (int t = 0; t < 4; ++t) {
    gacc[t] = (f32x4){0.f, 0.f, 0.f, 0.f};
    glo[t]  = (f32x4){0.f, 0.f, 0.f, 0.f};
  }

  for (int ch = 0; ch < nch; ++ch) {
    const float* xo = x0 + ch * CH * NK;
    float* yo = y + ch * CH * NK;

    // ---- stage Y' = 0.9Y+0.1X0 as f16 hi/lo ----
#pragma unroll
    for (int q = 0; q < 4; ++q) {
      int fi = (q * NT + tid) * 4;
      int r = fi >> 6, c = fi & 63;
      float4 yv = *(const float4*)(yo + fi);
      float4 xv = *(const float4*)(xo + fi);
      float p0 = fmaf(0.9f, yv.x, 0.1f * xv.x);
      float p1 = fmaf(0.9f, yv.y, 0.1f * xv.y);
      float p2 = fmaf(0.9f, yv.z, 0.1f * xv.z);
      float p3 = fmaf(0.9f, yv.w, 0.1f * xv.w);
      _Float16 h0 = (_Float16)p0, h1 = (_Float16)p1;
      _Float16 h2 = (_Float16)p2, h3 = (_Float16)p3;
      *(h4*)&sm.zt.a[r][c] = (h4){h0, h1, h2, h3};
      *(h4*)&sm.zt.b[r][c] = (h4){(_Float16)((p0 - (float)h0) * 2048.f),
                                  (_Float16)((p1 - (float)h1) * 2048.f),
                                  (_Float16)((p2 - (float)h2) * 2048.f),
                                  (_Float16)((p3 - (float)h3) * 2048.f)};
    }
    __syncthreads();

    // ---- dot = Y' @ S2 via MFMA (wave wv owns rows 16wv..16wv+15) ----
    h8 a_h[2], a_l[2];
#pragma unroll
    for (int kh = 0; kh < 2; ++kh) {
      a_h[kh] = *(const h8*)&sm.zt.a[16 * wv + lr][8 * lq + 32 * kh];
      a_l[kh] = *(const h8*)&sm.zt.b[16 * wv + lr][8 * lq + 32 * kh];
    }
    f32x4 dot[4];
#pragma unroll
    for (int tc = 0; tc < 4; ++tc) {
      f32x4 ah = (f32x4){0.f, 0.f, 0.f, 0.f};
      f32x4 al = (f32x4){0.f, 0.f, 0.f, 0.f};
#pragma unroll
      for (int kh = 0; kh < 2; ++kh) {
        ah = MFMA16x32(a_h[kh], sb_h[tc][kh], ah);
        al = MFMA16x32(a_h[kh], sb_l[tc][kh], al);
        al = MFMA16x32(a_l[kh], sb_h[tc][kh], al);
      }
      dot[tc] = ah + al * (1.f / 2048.f);
    }
    __syncthreads();   // all A-frag reads complete before Zt overwrite

    // ---- epilogue: Ynew = relu(dot) -> global; Zt f16 hi/lo -> LDS ----
    const int R0 = 16 * wv + 4 * lq;
#pragma unroll
    for (int tc = 0; tc < 4; ++tc) {
      const int C = 16 * tc + lr;
      float yn[4];
#pragma unroll
      for (int r_ = 0; r_ < 4; ++r_) {
        yn[r_] = fmaxf(dot[tc][r_], 0.f);
        yo[(R0 + r_) * NK + C] = yn[r_];
      }
      if (!last) {
        h4 zh, zl;
#pragma unroll
        for (int r_ = 0; r_ < 4; ++r_) {
          float z = fmaf(0.9f, yn[r_], 0.1f * xo[(R0 + r_) * NK + C]);
          _Float16 hh = (_Float16)z;
          zh[r_] = hh;
          zl[r_] = (_Float16)((z - (float)hh) * 2048.f);
        }
        *(h4*)&sm.zt.a[C][R0] = zh;    // transposed, b64 store
        *(h4*)&sm.zt.b[C][R0] = zl;
      }
    }
    __syncthreads();

    // ---- gram += Z^T Z via MFMA ----
    if (!last) {
      h8 ga_h[2], ga_l[2];
#pragma unroll
      for (int kh = 0; kh < 2; ++kh) {
        ga_h[kh] = *(const h8*)&sm.zt.a[16 * wv + lr][8 * lq + 32 * kh];
        ga_l[kh] = *(const h8*)&sm.zt.b[16 * wv + lr][8 * lq + 32 * kh];
      }
#pragma unroll
      for (int tc = 0; tc < 4; ++tc) {
        f32x4 lt = (f32x4){0.f, 0.f, 0.f, 0.f};
#pragma unroll
        for (int kh = 0; kh < 2; ++kh) {
          h8 gb_h = *(const h8*)&sm.zt.a[16 * tc + lr][8 * lq + 32 * kh];
          h8 gb_l = *(const h8*)&sm.zt.b[16 * tc + lr][8 * lq + 32 * kh];
          gacc[tc] = MFMA16x32(ga_h[kh], gb_h, gacc[tc]);
          lt = MFMA16x32(ga_h[kh], gb_l, lt);
          lt = MFMA16x32(ga_l[kh], gb_h, lt);
        }
        glo[tc] += lt;
      }
    }
    __syncthreads();   // before next chunk's staging overwrite
  }

  if (!last) {
    // partials store: G symmetric -> store transposed tile as coalesced f4
    float* p = partials + (size_t)blk * NK * NK;
    const int R0 = 16 * wv + 4 * lq;
#pragma unroll
    for (int tc = 0; tc < 4; ++tc) {
      const int C = 16 * tc + lr;
      float4 g = make_float4(gacc[tc][0] + glo[tc][0] * (1.f / 2048.f),
                             gacc[tc][1] + glo[tc][1] * (1.f / 2048.f),
                             gacc[tc][2] + glo[tc][2] * (1.f / 2048.f),
                             gacc[tc][3] + glo[tc][3] * (1.f / 2048.f));
      *(float4*)(p + C * NK + R0) = g;
    }
    __syncthreads();   // drain partial stores (barrier waits vmcnt)

    if (tid == 0) {
      __threadfence();
      unsigned old = atomicAdd(&cnt[b], 1u);
      sm.ns.tail = (((old + 1) & (unsigned)(bpb - 1)) == 0u) ? 1 : 0;
    }
    __syncthreads();
    if (sm.ns.tail) {
      __threadfence();
      ns_compute(sm, partials + (size_t)b * bpb * NK * NK, bpb,
                 (_Float16*)S2h + (size_t)b * NK * NK,
                 (_Float16*)S2l + (size_t)b * NK * NK, tid);
    }
  }
}

// ---------------------------------------------------------------------------
extern "C" void kernel_launch(void* const* d_in, const int* in_sizes, int n_in,
                              void* d_out, int out_size, void* d_ws,
                              size_t ws_size, hipStream_t stream) {
  (void)in_sizes; (void)n_in; (void)out_size;
  const float* X0 = (const float*)d_in[0];
  float* Y = (float*)d_out;

  const size_t slotf = (size_t)NK * NK;  // 4096
  const size_t need5 = ((size_t)(BATCH << 5)) * slotf * 4   // partials 16.8MB
                       + 2 * (size_t)BATCH * slotf * 2      // S2 hi/lo 0.5MB
                       + BATCH * sizeof(unsigned);
  const int shift = (ws_size >= need5) ? 5 : 4;
  const int nblk = BATCH << shift;

  float* partials = (float*)d_ws;
  _Float16* S2h = (_Float16*)((char*)d_ws + (size_t)nblk * slotf * 4);
  _Float16* S2l = S2h + (size_t)BATCH * slotf;
  unsigned* cnt = (unsigned*)(S2l + (size_t)BATCH * slotf);

  k_init<<<nblk, NT, 0, stream>>>(X0, Y, partials, cnt, shift);
  k_ns_once<<<BATCH, NT, 0, stream>>>(partials, S2h, S2l, 1 << shift);
  for (int t = 0; t < NITER; ++t) {
    k_fused<<<nblk, NT, 0, stream>>>(X0, Y, S2h, S2l, partials, cnt,
                                     t == NITER - 1 ? 1 : 0, shift);
  }
}

// Round 9
// 14469.495 us; speedup vs baseline: 1.2501x; 1.2501x over previous
//
#include <hip/hip_runtime.h>

// NSAFlowLayer: B=32 flows of (P=16384, K=64), 50 iters:
//   Y' = 0.9Y+0.1X0 ; S = NS_invsqrt(Y'^T Y') ; Y = relu(Y' @ (I+S)/2)
// R7 -> R8: REVERT inline-NS tail (caused 2-wave scheduling + per-batch
// straggler serialization + 22.7M LDS conflicts). Keep: S2=(I+S)/2 fold,
// S2 B-frags in registers, b64 Zt stores, transposed-f4 partials store.
// NEW: k_fused LDS = 18.4KB only -> 5+ blocks/CU (lb 256,5). k_ns rewritten
// on MFMA (NS iterates are symmetric polynomials in M -> row-read B-frags;
// f16 hi/lo planes), ~72 MFMA/wave/iter instead of ~12k VALU FMA/thread.
// R8b: fix clang error (vector-element ref binding in split16 call).

#define BATCH 32
#define NP    16384
#define NK    64
#define NITER 50
#define NSIT  8
#define EPSC  1e-8f
#define CH    64
#define NT    256
#define SP    68               // f32 LDS stride (k_init)
#define SPH   72               // f16 LDS stride (144B rows, 16B-aligned)

using h4    = __attribute__((ext_vector_type(4))) _Float16;
using h8    = __attribute__((ext_vector_type(8))) _Float16;
using f32x4 = __attribute__((ext_vector_type(4))) float;

#define MFMA16x32(A, B, C) __builtin_amdgcn_mfma_f32_16x16x32_f16(A, B, C, 0, 0, 0)

#define FMA16(D, A0, A1, A2, A3, BV) do {                                  \
  D[0][0] = fmaf(A0, BV.x, D[0][0]); D[0][1] = fmaf(A0, BV.y, D[0][1]);    \
  D[0][2] = fmaf(A0, BV.z, D[0][2]); D[0][3] = fmaf(A0, BV.w, D[0][3]);    \
  D[1][0] = fmaf(A1, BV.x, D[1][0]); D[1][1] = fmaf(A1, BV.y, D[1][1]);    \
  D[1][2] = fmaf(A1, BV.z, D[1][2]); D[1][3] = fmaf(A1, BV.w, D[1][3]);    \
  D[2][0] = fmaf(A2, BV.x, D[2][0]); D[2][1] = fmaf(A2, BV.y, D[2][1]);    \
  D[2][2] = fmaf(A2, BV.z, D[2][2]); D[2][3] = fmaf(A2, BV.w, D[2][3]);    \
  D[3][0] = fmaf(A3, BV.x, D[3][0]); D[3][1] = fmaf(A3, BV.y, D[3][1]);    \
  D[3][2] = fmaf(A3, BV.z, D[3][2]); D[3][3] = fmaf(A3, BV.w, D[3][3]);    \
} while (0)

__device__ __forceinline__ void split16(float v, _Float16& hi, _Float16& lo) {
  hi = (_Float16)v;
  lo = (_Float16)((v - (float)hi) * 2048.f);
}

// ---------------------------------------------------------------------------
// k_init: Y := X0 ; gram partials of Y'_0 (= X0). f32 VALU, runs once.
// ---------------------------------------------------------------------------
__global__ __launch_bounds__(NT, 4) void k_init(const float* __restrict__ X0,
                                                float* __restrict__ Y,
                                                float* __restrict__ partials,
                                                int shift) {
  __shared__ float sZ[CH][SP];
  const int tid = threadIdx.x, blk = blockIdx.x;
  const int bpb = 1 << shift;
  const int b = blk >> shift, rb = blk & (bpb - 1);
  const int rpb = NP >> shift, nch = rpb / CH;
  const size_t base = ((size_t)b * NP + (size_t)rb * rpb) * NK;
  const float* __restrict__ x0 = X0 + base;
  float* __restrict__ y = Y + base;
  const int it = tid >> 4, jt = tid & 15;
  const int i0 = it * 4, j0 = jt * 4;
  float acc[4][4] = {{0.f}};

  for (int ch = 0; ch < nch; ++ch) {
    const float* xo = x0 + ch * CH * NK;
    float* yo = y + ch * CH * NK;
#pragma unroll
    for (int q = 0; q < 4; ++q) {
      int fi = (q * NT + tid) * 4;
      float4 xv = *(const float4*)(xo + fi);
      *(float4*)(yo + fi) = xv;
      int r = fi >> 6, c = fi & 63;
      *(float4*)&sZ[r][c] = xv;
    }
    __syncthreads();
#pragma unroll 8
    for (int r = 0; r < CH; ++r) {
      float4 zi = *(const float4*)&sZ[r][i0];
      float4 zj = *(const float4*)&sZ[r][j0];
      FMA16(acc, zi.x, zi.y, zi.z, zi.w, zj);
    }
    __syncthreads();
  }
  float* p = partials + (size_t)blk * NK * NK;
#pragma unroll
  for (int a = 0; a < 4; ++a)
    *(float4*)(p + (i0 + a) * NK + j0) =
        make_float4(acc[a][0], acc[a][1], acc[a][2], acc[a][3]);
}

// ---------------------------------------------------------------------------
// k_ns (MFMA): per batch, M = sum(partials); 8 coupled NS iters with all
// matrices as f16 hi/lo planes in LDS (symmetric -> B-frags are row reads).
// Emits S2 = (I + Z/sqrt(nrm))/2 as f16 hi/lo. One 256-thread block / batch.
// ---------------------------------------------------------------------------
__global__ __launch_bounds__(NT, 2) void k_ns(const float* __restrict__ partials,
                                              _Float16* __restrict__ S2h,
                                              _Float16* __restrict__ S2l,
                                              int npart) {
  __shared__ _Float16 Ah[NK][SPH], Al[NK][SPH];  // NS "Y" hi/lo
  __shared__ _Float16 Bh[NK][SPH], Bl[NK][SPH];  // NS "Z" hi/lo
  __shared__ _Float16 Th[NK][SPH], Tl[NK][SPH];  // NS "T" hi/lo
  __shared__ float red[16];

  const int tid = threadIdx.x, b = blockIdx.x;
  const int it = tid >> 4, jt = tid & 15;
  const int i0 = it * 4, j0 = jt * 4;

  // ---- f32 reduction of partial grams ----
  float m[4][4] = {{0.f}};
  const float* pb = partials + (size_t)b * npart * NK * NK;
#pragma unroll 4
  for (int p = 0; p < npart; ++p) {
    const float* pp = pb + (size_t)p * NK * NK;
#pragma unroll
    for (int a = 0; a < 4; ++a) {
      float4 v = *(const float4*)(pp + (i0 + a) * NK + j0);
      m[a][0] += v.x; m[a][1] += v.y; m[a][2] += v.z; m[a][3] += v.w;
    }
  }
  if (it == jt) red[it] = m[0][0] + m[1][1] + m[2][2] + m[3][3];
  __syncthreads();
  float nrm = EPSC;
#pragma unroll
  for (int i = 0; i < 16; ++i) nrm += red[i];
  const float inv = 1.0f / nrm;

  // Y0 = M/nrm (hi/lo), Z0 = I
#pragma unroll
  for (int a = 0; a < 4; ++a)
#pragma unroll
    for (int c = 0; c < 4; ++c) {
      _Float16 hh, ll;
      split16(m[a][c] * inv, hh, ll);
      Ah[i0 + a][j0 + c] = hh;  Al[i0 + a][j0 + c] = ll;
      Bh[i0 + a][j0 + c] = ((i0 + a) == (j0 + c)) ? (_Float16)1.0f
                                                  : (_Float16)0.0f;
      Bl[i0 + a][j0 + c] = (_Float16)0.0f;
    }
  __syncthreads();

  const int wv = tid >> 6, ln = tid & 63;
  const int lr = ln & 15, lq = ln >> 4;
  const int R0 = 16 * wv + 4 * lq;

  for (int ns = 0; ns < NSIT; ++ns) {
    // ---- D = Z @ Y ; T = 1.5I - 0.5D ----
    h8 za_h[2], za_l[2];
#pragma unroll
    for (int kh = 0; kh < 2; ++kh) {
      za_h[kh] = *(const h8*)&Bh[16 * wv + lr][8 * lq + 32 * kh];
      za_l[kh] = *(const h8*)&Bl[16 * wv + lr][8 * lq + 32 * kh];
    }
#pragma unroll
    for (int tc = 0; tc < 4; ++tc) {
      f32x4 dh = (f32x4){0.f, 0.f, 0.f, 0.f};
      f32x4 dl = (f32x4){0.f, 0.f, 0.f, 0.f};
#pragma unroll
      for (int kh = 0; kh < 2; ++kh) {
        h8 yb_h = *(const h8*)&Ah[16 * tc + lr][8 * lq + 32 * kh];
        h8 yb_l = *(const h8*)&Al[16 * tc + lr][8 * lq + 32 * kh];
        dh = MFMA16x32(za_h[kh], yb_h, dh);
        dl = MFMA16x32(za_h[kh], yb_l, dl);
        dl = MFMA16x32(za_l[kh], yb_h, dl);
      }
      const int C = 16 * tc + lr;
#pragma unroll
      for (int r_ = 0; r_ < 4; ++r_) {
        float d = dh[r_] + dl[r_] * (1.f / 2048.f);
        float t = (((R0 + r_) == C) ? 1.5f : 0.0f) - 0.5f * d;
        _Float16 hh, ll;
        split16(t, hh, ll);
        Th[R0 + r_][C] = hh;  Tl[R0 + r_][C] = ll;
      }
    }
    __syncthreads();

    // ---- r1 = Y @ T ; r2 = T @ Z (into regs) ----
    h8 ya_h[2], ya_l[2], ta_h[2], ta_l[2];
#pragma unroll
    for (int kh = 0; kh < 2; ++kh) {
      ya_h[kh] = *(const h8*)&Ah[16 * wv + lr][8 * lq + 32 * kh];
      ya_l[kh] = *(const h8*)&Al[16 * wv + lr][8 * lq + 32 * kh];
      ta_h[kh] = *(const h8*)&Th[16 * wv + lr][8 * lq + 32 * kh];
      ta_l[kh] = *(const h8*)&Tl[16 * wv + lr][8 * lq + 32 * kh];
    }
    f32x4 r1h[4], r1l[4], r2h[4], r2l[4];
#pragma unroll
    for (int tc = 0; tc < 4; ++tc) {
      r1h[tc] = (f32x4){0.f, 0.f, 0.f, 0.f};
      r1l[tc] = (f32x4){0.f, 0.f, 0.f, 0.f};
      r2h[tc] = (f32x4){0.f, 0.f, 0.f, 0.f};
      r2l[tc] = (f32x4){0.f, 0.f, 0.f, 0.f};
#pragma unroll
      for (int kh = 0; kh < 2; ++kh) {
        h8 tb_h = *(const h8*)&Th[16 * tc + lr][8 * lq + 32 * kh];
        h8 tb_l = *(const h8*)&Tl[16 * tc + lr][8 * lq + 32 * kh];
        r1h[tc] = MFMA16x32(ya_h[kh], tb_h, r1h[tc]);
        r1l[tc] = MFMA16x32(ya_h[kh], tb_l, r1l[tc]);
        r1l[tc] = MFMA16x32(ya_l[kh], tb_h, r1l[tc]);
        h8 zb_h = *(const h8*)&Bh[16 * tc + lr][8 * lq + 32 * kh];
        h8 zb_l = *(const h8*)&Bl[16 * tc + lr][8 * lq + 32 * kh];
        r2h[tc] = MFMA16x32(ta_h[kh], zb_h, r2h[tc]);
        r2l[tc] = MFMA16x32(ta_h[kh], zb_l, r2l[tc]);
        r2l[tc] = MFMA16x32(ta_l[kh], zb_h, r2l[tc]);
      }
    }
    __syncthreads();   // all reads of A/B/T complete before overwrite

    // ---- write back Y = r1, Z = r2 (hi/lo split) ----
#pragma unroll
    for (int tc = 0; tc < 4; ++tc) {
      const int C = 16 * tc + lr;
#pragma unroll
      for (int r_ = 0; r_ < 4; ++r_) {
        _Float16 hh, ll;
        split16(r1h[tc][r_] + r1l[tc][r_] * (1.f / 2048.f), hh, ll);
        Ah[R0 + r_][C] = hh;  Al[R0 + r_][C] = ll;
        split16(r2h[tc][r_] + r2l[tc][r_] * (1.f / 2048.f), hh, ll);
        Bh[R0 + r_][C] = hh;  Bl[R0 + r_][C] = ll;
      }
    }
    __syncthreads();
  }

  // ---- emit S2 = 0.5I + (0.5/sqrt(nrm)) * Z ----
  const float sc = 0.5f / sqrtf(nrm);
  _Float16* sh = S2h + (size_t)b * NK * NK;
  _Float16* sl = S2l + (size_t)b * NK * NK;
#pragma unroll
  for (int a = 0; a < 4; ++a)
#pragma unroll
    for (int c = 0; c < 4; ++c) {
      float z = (float)Bh[i0 + a][j0 + c] +
                (float)Bl[i0 + a][j0 + c] * (1.f / 2048.f);
      float s = z * sc + (((i0 + a) == (j0 + c)) ? 0.5f : 0.0f);
      _Float16 hh, ll;
      split16(s, hh, ll);
      sh[(i0 + a) * NK + (j0 + c)] = hh;
      sl[(i0 + a) * NK + (j0 + c)] = ll;
    }
}

// ---------------------------------------------------------------------------
// k_fused: Ynew = relu(Y' @ S2), Y' = 0.9Y+0.1X0 ; write Y.
// If !last: Zt = (0.9Ynew+0.1X0)^T staged f16 hi/lo, gram via MFMA,
// partials stored transposed-f4 (G exactly symmetric). LDS 18.4KB.
// ---------------------------------------------------------------------------
__global__ __launch_bounds__(NT, 5) void k_fused(
    const float* __restrict__ X0, float* __restrict__ Y,
    const _Float16* __restrict__ S2h, const _Float16* __restrict__ S2l,
    float* __restrict__ partials, int last, int shift) {
  __shared__ _Float16 sYa[CH][SPH];  // Y' hi  -> Zt hi after epilogue
  __shared__ _Float16 sYb[CH][SPH];  // Y' lo  -> Zt lo

  const int tid = threadIdx.x, blk = blockIdx.x;
  const int bpb = 1 << shift;
  const int b = blk >> shift, rb = blk & (bpb - 1);
  const int rpb = NP >> shift, nch = rpb / CH;
  const size_t base = ((size_t)b * NP + (size_t)rb * rpb) * NK;
  const float* __restrict__ x0 = X0 + base;
  float* __restrict__ y = Y + base;

  const int wv = tid >> 6, ln = tid & 63;
  const int lr = ln & 15, lq = ln >> 4;

  // S2 B-fragments in registers (S2 symmetric -> row reads), L2-hot
  h8 sb_h[4][2], sb_l[4][2];
  {
    const _Float16* s2h = S2h + (size_t)b * NK * NK;
    const _Float16* s2l = S2l + (size_t)b * NK * NK;
#pragma unroll
    for (int tc = 0; tc < 4; ++tc)
#pragma unroll
      for (int kh = 0; kh < 2; ++kh) {
        int off = (16 * tc + lr) * NK + 32 * kh + 8 * lq;
        sb_h[tc][kh] = *(const h8*)(s2h + off);
        sb_l[tc][kh] = *(const h8*)(s2l + off);
      }
  }

  f32x4 gacc[4], glo[4];
#pragma unroll
  for (int t = 0; t < 4; ++t) {
    gacc[t] = (f32x4){0.f, 0.f, 0.f, 0.f};
    glo[t]  = (f32x4){0.f, 0.f, 0.f, 0.f};
  }

  for (int ch = 0; ch < nch; ++ch) {
    const float* xo = x0 + ch * CH * NK;
    float* yo = y + ch * CH * NK;

    // ---- stage Y' = 0.9Y+0.1X0 as f16 hi/lo ----
#pragma unroll
    for (int q = 0; q < 4; ++q) {
      int fi = (q * NT + tid) * 4;
      int r = fi >> 6, c = fi & 63;
      float4 yv = *(const float4*)(yo + fi);
      float4 xv = *(const float4*)(xo + fi);
      float p0 = fmaf(0.9f, yv.x, 0.1f * xv.x);
      float p1 = fmaf(0.9f, yv.y, 0.1f * xv.y);
      float p2 = fmaf(0.9f, yv.z, 0.1f * xv.z);
      float p3 = fmaf(0.9f, yv.w, 0.1f * xv.w);
      _Float16 h0, l0, h1, l1, h2, l2, h3, l3;
      split16(p0, h0, l0); split16(p1, h1, l1);
      split16(p2, h2, l2); split16(p3, h3, l3);
      *(h4*)&sYa[r][c] = (h4){h0, h1, h2, h3};
      *(h4*)&sYb[r][c] = (h4){l0, l1, l2, l3};
    }
    __syncthreads();

    // ---- dot = Y' @ S2 via MFMA (wave wv owns rows 16wv..16wv+15) ----
    h8 a_h[2], a_l[2];
#pragma unroll
    for (int kh = 0; kh < 2; ++kh) {
      a_h[kh] = *(const h8*)&sYa[16 * wv + lr][8 * lq + 32 * kh];
      a_l[kh] = *(const h8*)&sYb[16 * wv + lr][8 * lq + 32 * kh];
    }
    f32x4 dot[4];
#pragma unroll
    for (int tc = 0; tc < 4; ++tc) {
      f32x4 ah = (f32x4){0.f, 0.f, 0.f, 0.f};
      f32x4 al = (f32x4){0.f, 0.f, 0.f, 0.f};
#pragma unroll
      for (int kh = 0; kh < 2; ++kh) {
        ah = MFMA16x32(a_h[kh], sb_h[tc][kh], ah);
        al = MFMA16x32(a_h[kh], sb_l[tc][kh], al);
        al = MFMA16x32(a_l[kh], sb_h[tc][kh], al);
      }
      dot[tc] = ah + al * (1.f / 2048.f);
    }
    __syncthreads();   // all A-frag reads complete before Zt overwrite

    // ---- epilogue: Ynew = relu(dot) -> global; Zt f16 hi/lo -> LDS ----
    const int R0 = 16 * wv + 4 * lq;
#pragma unroll
    for (int tc = 0; tc < 4; ++tc) {
      const int C = 16 * tc + lr;
      float yn[4];
#pragma unroll
      for (int r_ = 0; r_ < 4; ++r_) {
        yn[r_] = fmaxf(dot[tc][r_], 0.f);
        yo[(R0 + r_) * NK + C] = yn[r_];
      }
      if (!last) {
        h4 zh, zl;
#pragma unroll
        for (int r_ = 0; r_ < 4; ++r_) {
          float z = fmaf(0.9f, yn[r_], 0.1f * xo[(R0 + r_) * NK + C]);
          _Float16 th, tl;           // locals: vector elements can't bind to refs
          split16(z, th, tl);
          zh[r_] = th;
          zl[r_] = tl;
        }
        *(h4*)&sYa[C][R0] = zh;    // transposed, b64 store
        *(h4*)&sYb[C][R0] = zl;
      }
    }
    __syncthreads();

    // ---- gram += Z^T Z via MFMA ----
    if (!last) {
      h8 ga_h[2], ga_l[2];
#pragma unroll
      for (int kh = 0; kh < 2; ++kh) {
        ga_h[kh] = *(const h8*)&sYa[16 * wv + lr][8 * lq + 32 * kh];
        ga_l[kh] = *(const h8*)&sYb[16 * wv + lr][8 * lq + 32 * kh];
      }
#pragma unroll
      for (int tc = 0; tc < 4; ++tc) {
        f32x4 lt = (f32x4){0.f, 0.f, 0.f, 0.f};
#pragma unroll
        for (int kh = 0; kh < 2; ++kh) {
          h8 gb_h = *(const h8*)&sYa[16 * tc + lr][8 * lq + 32 * kh];
          h8 gb_l = *(const h8*)&sYb[16 * tc + lr][8 * lq + 32 * kh];
          gacc[tc] = MFMA16x32(ga_h[kh], gb_h, gacc[tc]);
          lt = MFMA16x32(ga_h[kh], gb_l, lt);
          lt = MFMA16x32(ga_l[kh], gb_h, lt);
        }
        glo[tc] += lt;
      }
    }
    __syncthreads();   // before next chunk's staging overwrite
  }

  if (!last) {
    // partials store: G exactly symmetric -> store transposed tile as f4
    float* p = partials + (size_t)blk * NK * NK;
    const int R0 = 16 * wv + 4 * lq;
#pragma unroll
    for (int tc = 0; tc < 4; ++tc) {
      const int C = 16 * tc + lr;
      float4 g = make_float4(gacc[tc][0] + glo[tc][0] * (1.f / 2048.f),
                             gacc[tc][1] + glo[tc][1] * (1.f / 2048.f),
                             gacc[tc][2] + glo[tc][2] * (1.f / 2048.f),
                             gacc[tc][3] + glo[tc][3] * (1.f / 2048.f));
      *(float4*)(p + C * NK + R0) = g;
    }
  }
}

// ---------------------------------------------------------------------------
extern "C" void kernel_launch(void* const* d_in, const int* in_sizes, int n_in,
                              void* d_out, int out_size, void* d_ws,
                              size_t ws_size, hipStream_t stream) {
  (void)in_sizes; (void)n_in; (void)out_size;
  const float* X0 = (const float*)d_in[0];
  float* Y = (float*)d_out;

  const size_t slotf = (size_t)NK * NK;  // 4096
  const size_t need5 = ((size_t)(BATCH << 5)) * slotf * 4   // partials 16.8MB
                       + 2 * (size_t)BATCH * slotf * 2;     // S2 hi/lo 0.5MB
  const int shift = (ws_size >= need5) ? 5 : 4;
  const int nblk = BATCH << shift;

  float* partials = (float*)d_ws;
  _Float16* S2h = (_Float16*)((char*)d_ws + (size_t)nblk * slotf * 4);
  _Float16* S2l = S2h + (size_t)BATCH * slotf;

  k_init<<<nblk, NT, 0, stream>>>(X0, Y, partials, shift);
  for (int t = 0; t < NITER; ++t) {
    k_ns<<<BATCH, NT, 0, stream>>>(partials, S2h, S2l, 1 << shift);
    k_fused<<<nblk, NT, 0, stream>>>(X0, Y, S2h, S2l, partials,
                                     t == NITER - 1 ? 1 : 0, shift);
  }
}

// Round 11
// 10483.772 us; speedup vs baseline: 1.7253x; 1.3802x over previous
//
#include <hip/hip_runtime.h>

// NSAFlowLayer: B=32 flows of (P=16384, K=64), 50 iters:
//   Y' = 0.9Y+0.1X0 ; S = NS_invsqrt(Y'^T Y') ; Y = relu(Y' @ (I+S)/2)
// R9 -> R10: kill the 3x HBM amplification (R9: 990MB/dispatch from scalar
// 4B Y-stores + scalar X0 re-reads). Now: (1) yn written to own-stripe LDS
// (hi/lo), read back coalesced, Y stored as float4 (same pattern as staging);
// (2) X0 chunk kept in registers (xv[4]) - no global re-read; (3) Zt in its
// own stride-68 buffer (conflict-free b64 gram reads, 4-way transposed
// stores). LDS 35.8KB -> 4 blocks/CU. k_ns (MFMA, ~17us) unchanged.

#define BATCH 32
#define NP    16384
#define NK    64
#define NITER 50
#define NSIT  8
#define EPSC  1e-8f
#define CH    64
#define NT    256
#define SP    68               // f32 LDS stride (k_init)
#define SPH   72               // f16 stride, 144B rows (16B-aligned b128)
#define SZP   68               // f16 stride for Zt, 136B rows (8B-aligned b64)

using h4    = __attribute__((ext_vector_type(4))) _Float16;
using h8    = __attribute__((ext_vector_type(8))) _Float16;
using f32x4 = __attribute__((ext_vector_type(4))) float;

#define MFMA16x32(A, B, C) __builtin_amdgcn_mfma_f32_16x16x32_f16(A, B, C, 0, 0, 0)

#define FMA16(D, A0, A1, A2, A3, BV) do {                                  \
  D[0][0] = fmaf(A0, BV.x, D[0][0]); D[0][1] = fmaf(A0, BV.y, D[0][1]);    \
  D[0][2] = fmaf(A0, BV.z, D[0][2]); D[0][3] = fmaf(A0, BV.w, D[0][3]);    \
  D[1][0] = fmaf(A1, BV.x, D[1][0]); D[1][1] = fmaf(A1, BV.y, D[1][1]);    \
  D[1][2] = fmaf(A1, BV.z, D[1][2]); D[1][3] = fmaf(A1, BV.w, D[1][3]);    \
  D[2][0] = fmaf(A2, BV.x, D[2][0]); D[2][1] = fmaf(A2, BV.y, D[2][1]);    \
  D[2][2] = fmaf(A2, BV.z, D[2][2]); D[2][3] = fmaf(A2, BV.w, D[2][3]);    \
  D[3][0] = fmaf(A3, BV.x, D[3][0]); D[3][1] = fmaf(A3, BV.y, D[3][1]);    \
  D[3][2] = fmaf(A3, BV.z, D[3][2]); D[3][3] = fmaf(A3, BV.w, D[3][3]);    \
} while (0)

__device__ __forceinline__ void split16(float v, _Float16& hi, _Float16& lo) {
  hi = (_Float16)v;
  lo = (_Float16)((v - (float)hi) * 2048.f);
}

// two b64 LDS reads -> h8 (for stride-68 Zt rows, 8B-aligned)
__device__ __forceinline__ h8 ld_h8_2x(const _Float16* p) {
  h4 a = *(const h4*)p;
  h4 b = *(const h4*)(p + 4);
  h8 r;
  r[0] = a[0]; r[1] = a[1]; r[2] = a[2]; r[3] = a[3];
  r[4] = b[0]; r[5] = b[1]; r[6] = b[2]; r[7] = b[3];
  return r;
}

// ---------------------------------------------------------------------------
// k_init: Y := X0 ; gram partials of Y'_0 (= X0). f32 VALU, runs once.
// ---------------------------------------------------------------------------
__global__ __launch_bounds__(NT, 4) void k_init(const float* __restrict__ X0,
                                                float* __restrict__ Y,
                                                float* __restrict__ partials,
                                                int shift) {
  __shared__ float sZ[CH][SP];
  const int tid = threadIdx.x, blk = blockIdx.x;
  const int bpb = 1 << shift;
  const int b = blk >> shift, rb = blk & (bpb - 1);
  const int rpb = NP >> shift, nch = rpb / CH;
  const size_t base = ((size_t)b * NP + (size_t)rb * rpb) * NK;
  const float* __restrict__ x0 = X0 + base;
  float* __restrict__ y = Y + base;
  const int it = tid >> 4, jt = tid & 15;
  const int i0 = it * 4, j0 = jt * 4;
  float acc[4][4] = {{0.f}};

  for (int ch = 0; ch < nch; ++ch) {
    const float* xo = x0 + ch * CH * NK;
    float* yo = y + ch * CH * NK;
#pragma unroll
    for (int q = 0; q < 4; ++q) {
      int fi = (q * NT + tid) * 4;
      float4 xv = *(const float4*)(xo + fi);
      *(float4*)(yo + fi) = xv;
      int r = fi >> 6, c = fi & 63;
      *(float4*)&sZ[r][c] = xv;
    }
    __syncthreads();
#pragma unroll 8
    for (int r = 0; r < CH; ++r) {
      float4 zi = *(const float4*)&sZ[r][i0];
      float4 zj = *(const float4*)&sZ[r][j0];
      FMA16(acc, zi.x, zi.y, zi.z, zi.w, zj);
    }
    __syncthreads();
  }
  float* p = partials + (size_t)blk * NK * NK;
#pragma unroll
  for (int a = 0; a < 4; ++a)
    *(float4*)(p + (i0 + a) * NK + j0) =
        make_float4(acc[a][0], acc[a][1], acc[a][2], acc[a][3]);
}

// ---------------------------------------------------------------------------
// k_ns (MFMA): per batch, M = sum(partials); 8 coupled NS iters, f16 hi/lo
// planes in LDS. Emits S2 = (I + Z/sqrt(nrm))/2 as f16 hi/lo. 1 block/batch.
// ---------------------------------------------------------------------------
__global__ __launch_bounds__(NT, 2) void k_ns(const float* __restrict__ partials,
                                              _Float16* __restrict__ S2h,
                                              _Float16* __restrict__ S2l,
                                              int npart) {
  __shared__ _Float16 Ah[NK][SPH], Al[NK][SPH];  // NS "Y" hi/lo
  __shared__ _Float16 Bh[NK][SPH], Bl[NK][SPH];  // NS "Z" hi/lo
  __shared__ _Float16 Th[NK][SPH], Tl[NK][SPH];  // NS "T" hi/lo
  __shared__ float red[16];

  const int tid = threadIdx.x, b = blockIdx.x;
  const int it = tid >> 4, jt = tid & 15;
  const int i0 = it * 4, j0 = jt * 4;

  float m[4][4] = {{0.f}};
  const float* pb = partials + (size_t)b * npart * NK * NK;
#pragma unroll 4
  for (int p = 0; p < npart; ++p) {
    const float* pp = pb + (size_t)p * NK * NK;
#pragma unroll
    for (int a = 0; a < 4; ++a) {
      float4 v = *(const float4*)(pp + (i0 + a) * NK + j0);
      m[a][0] += v.x; m[a][1] += v.y; m[a][2] += v.z; m[a][3] += v.w;
    }
  }
  if (it == jt) red[it] = m[0][0] + m[1][1] + m[2][2] + m[3][3];
  __syncthreads();
  float nrm = EPSC;
#pragma unroll
  for (int i = 0; i < 16; ++i) nrm += red[i];
  const float inv = 1.0f / nrm;

#pragma unroll
  for (int a = 0; a < 4; ++a)
#pragma unroll
    for (int c = 0; c < 4; ++c) {
      _Float16 hh, ll;
      split16(m[a][c] * inv, hh, ll);
      Ah[i0 + a][j0 + c] = hh;  Al[i0 + a][j0 + c] = ll;
      Bh[i0 + a][j0 + c] = ((i0 + a) == (j0 + c)) ? (_Float16)1.0f
                                                  : (_Float16)0.0f;
      Bl[i0 + a][j0 + c] = (_Float16)0.0f;
    }
  __syncthreads();

  const int wv = tid >> 6, ln = tid & 63;
  const int lr = ln & 15, lq = ln >> 4;
  const int R0 = 16 * wv + 4 * lq;

  for (int ns = 0; ns < NSIT; ++ns) {
    // D = Z @ Y ; T = 1.5I - 0.5D
    h8 za_h[2], za_l[2];
#pragma unroll
    for (int kh = 0; kh < 2; ++kh) {
      za_h[kh] = *(const h8*)&Bh[16 * wv + lr][8 * lq + 32 * kh];
      za_l[kh] = *(const h8*)&Bl[16 * wv + lr][8 * lq + 32 * kh];
    }
#pragma unroll
    for (int tc = 0; tc < 4; ++tc) {
      f32x4 dh = (f32x4){0.f, 0.f, 0.f, 0.f};
      f32x4 dl = (f32x4){0.f, 0.f, 0.f, 0.f};
#pragma unroll
      for (int kh = 0; kh < 2; ++kh) {
        h8 yb_h = *(const h8*)&Ah[16 * tc + lr][8 * lq + 32 * kh];
        h8 yb_l = *(const h8*)&Al[16 * tc + lr][8 * lq + 32 * kh];
        dh = MFMA16x32(za_h[kh], yb_h, dh);
        dl = MFMA16x32(za_h[kh], yb_l, dl);
        dl = MFMA16x32(za_l[kh], yb_h, dl);
      }
      const int C = 16 * tc + lr;
#pragma unroll
      for (int r_ = 0; r_ < 4; ++r_) {
        float d = dh[r_] + dl[r_] * (1.f / 2048.f);
        float t = (((R0 + r_) == C) ? 1.5f : 0.0f) - 0.5f * d;
        _Float16 hh, ll;
        split16(t, hh, ll);
        Th[R0 + r_][C] = hh;  Tl[R0 + r_][C] = ll;
      }
    }
    __syncthreads();

    // r1 = Y @ T ; r2 = T @ Z
    h8 ya_h[2], ya_l[2], ta_h[2], ta_l[2];
#pragma unroll
    for (int kh = 0; kh < 2; ++kh) {
      ya_h[kh] = *(const h8*)&Ah[16 * wv + lr][8 * lq + 32 * kh];
      ya_l[kh] = *(const h8*)&Al[16 * wv + lr][8 * lq + 32 * kh];
      ta_h[kh] = *(const h8*)&Th[16 * wv + lr][8 * lq + 32 * kh];
      ta_l[kh] = *(const h8*)&Tl[16 * wv + lr][8 * lq + 32 * kh];
    }
    f32x4 r1h[4], r1l[4], r2h[4], r2l[4];
#pragma unroll
    for (int tc = 0; tc < 4; ++tc) {
      r1h[tc] = (f32x4){0.f, 0.f, 0.f, 0.f};
      r1l[tc] = (f32x4){0.f, 0.f, 0.f, 0.f};
      r2h[tc] = (f32x4){0.f, 0.f, 0.f, 0.f};
      r2l[tc] = (f32x4){0.f, 0.f, 0.f, 0.f};
#pragma unroll
      for (int kh = 0; kh < 2; ++kh) {
        h8 tb_h = *(const h8*)&Th[16 * tc + lr][8 * lq + 32 * kh];
        h8 tb_l = *(const h8*)&Tl[16 * tc + lr][8 * lq + 32 * kh];
        r1h[tc] = MFMA16x32(ya_h[kh], tb_h, r1h[tc]);
        r1l[tc] = MFMA16x32(ya_h[kh], tb_l, r1l[tc]);
        r1l[tc] = MFMA16x32(ya_l[kh], tb_h, r1l[tc]);
        h8 zb_h = *(const h8*)&Bh[16 * tc + lr][8 * lq + 32 * kh];
        h8 zb_l = *(const h8*)&Bl[16 * tc + lr][8 * lq + 32 * kh];
        r2h[tc] = MFMA16x32(ta_h[kh], zb_h, r2h[tc]);
        r2l[tc] = MFMA16x32(ta_h[kh], zb_l, r2l[tc]);
        r2l[tc] = MFMA16x32(ta_l[kh], zb_h, r2l[tc]);
      }
    }
    __syncthreads();

#pragma unroll
    for (int tc = 0; tc < 4; ++tc) {
      const int C = 16 * tc + lr;
#pragma unroll
      for (int r_ = 0; r_ < 4; ++r_) {
        _Float16 hh, ll;
        split16(r1h[tc][r_] + r1l[tc][r_] * (1.f / 2048.f), hh, ll);
        Ah[R0 + r_][C] = hh;  Al[R0 + r_][C] = ll;
        split16(r2h[tc][r_] + r2l[tc][r_] * (1.f / 2048.f), hh, ll);
        Bh[R0 + r_][C] = hh;  Bl[R0 + r_][C] = ll;
      }
    }
    __syncthreads();
  }

  const float sc = 0.5f / sqrtf(nrm);
  _Float16* sh = S2h + (size_t)b * NK * NK;
  _Float16* sl = S2l + (size_t)b * NK * NK;
#pragma unroll
  for (int a = 0; a < 4; ++a)
#pragma unroll
    for (int c = 0; c < 4; ++c) {
      float z = (float)Bh[i0 + a][j0 + c] +
                (float)Bl[i0 + a][j0 + c] * (1.f / 2048.f);
      float s = z * sc + (((i0 + a) == (j0 + c)) ? 0.5f : 0.0f);
      _Float16 hh, ll;
      split16(s, hh, ll);
      sh[(i0 + a) * NK + (j0 + c)] = hh;
      sl[(i0 + a) * NK + (j0 + c)] = ll;
    }
}

// ---------------------------------------------------------------------------
// k_fused: Ynew = relu(Y' @ S2), Y' = 0.9Y+0.1X0 ; Y stored float4-coalesced
// via LDS round-trip; X0 kept in regs; Zt staged (stride 68) for gram MFMA.
// ---------------------------------------------------------------------------
__global__ __launch_bounds__(NT, 4) void k_fused(
    const float* __restrict__ X0, float* __restrict__ Y,
    const _Float16* __restrict__ S2h, const _Float16* __restrict__ S2l,
    float* __restrict__ partials, int last, int shift) {
  __shared__ _Float16 sYa[CH][SPH], sYb[CH][SPH];  // Y' hi/lo -> yn hi/lo
  __shared__ _Float16 sZa[CH][SZP], sZb[CH][SZP];  // Zt hi/lo (transposed)

  const int tid = threadIdx.x, blk = blockIdx.x;
  const int bpb = 1 << shift;
  const int b = blk >> shift, rb = blk & (bpb - 1);
  const int rpb = NP >> shift, nch = rpb / CH;
  const size_t base = ((size_t)b * NP + (size_t)rb * rpb) * NK;
  const float* __restrict__ x0 = X0 + base;
  float* __restrict__ y = Y + base;

  const int wv = tid >> 6, ln = tid & 63;
  const int lr = ln & 15, lq = ln >> 4;
  const int R0 = 16 * wv + 4 * lq;

  // S2 B-fragments (S2 symmetric -> row reads), L2-hot
  h8 sb_h[4][2], sb_l[4][2];
  {
    const _Float16* s2h = S2h + (size_t)b * NK * NK;
    const _Float16* s2l = S2l + (size_t)b * NK * NK;
#pragma unroll
    for (int tc = 0; tc < 4; ++tc)
#pragma unroll
      for (int kh = 0; kh < 2; ++kh) {
        int off = (16 * tc + lr) * NK + 32 * kh + 8 * lq;
        sb_h[tc][kh] = *(const h8*)(s2h + off);
        sb_l[tc][kh] = *(const h8*)(s2l + off);
      }
  }

  f32x4 gacc[4], glo[4];
#pragma unroll
  for (int t = 0; t < 4; ++t) {
    gacc[t] = (f32x4){0.f, 0.f, 0.f, 0.f};
    glo[t]  = (f32x4){0.f, 0.f, 0.f, 0.f};
  }

  for (int ch = 0; ch < nch; ++ch) {
    const float* xo = x0 + ch * CH * NK;
    float* yo = y + ch * CH * NK;

    // ---- phase 1: stage Y' hi/lo; keep X0 chunk in regs ----
    float4 xv[4];
#pragma unroll
    for (int q = 0; q < 4; ++q) {
      int fi = (q * NT + tid) * 4;
      int r = fi >> 6, c = fi & 63;
      float4 yv = *(const float4*)(yo + fi);
      xv[q] = *(const float4*)(xo + fi);
      float p0 = fmaf(0.9f, yv.x, 0.1f * xv[q].x);
      float p1 = fmaf(0.9f, yv.y, 0.1f * xv[q].y);
      float p2 = fmaf(0.9f, yv.z, 0.1f * xv[q].z);
      float p3 = fmaf(0.9f, yv.w, 0.1f * xv[q].w);
      _Float16 h0, l0, h1, l1, h2, l2, h3, l3;
      split16(p0, h0, l0); split16(p1, h1, l1);
      split16(p2, h2, l2); split16(p3, h3, l3);
      *(h4*)&sYa[r][c] = (h4){h0, h1, h2, h3};
      *(h4*)&sYb[r][c] = (h4){l0, l1, l2, l3};
    }
    __syncthreads();

    // ---- phase 2: dot = Y' @ S2 (A from own stripe, B regs) ----
    h8 a_h[2], a_l[2];
#pragma unroll
    for (int kh = 0; kh < 2; ++kh) {
      a_h[kh] = *(const h8*)&sYa[16 * wv + lr][8 * lq + 32 * kh];
      a_l[kh] = *(const h8*)&sYb[16 * wv + lr][8 * lq + 32 * kh];
    }
    f32x4 dot[4];
#pragma unroll
    for (int tc = 0; tc < 4; ++tc) {
      f32x4 ah = (f32x4){0.f, 0.f, 0.f, 0.f};
      f32x4 al = (f32x4){0.f, 0.f, 0.f, 0.f};
#pragma unroll
      for (int kh = 0; kh < 2; ++kh) {
        ah = MFMA16x32(a_h[kh], sb_h[tc][kh], ah);
        al = MFMA16x32(a_h[kh], sb_l[tc][kh], al);
        al = MFMA16x32(a_l[kh], sb_h[tc][kh], al);
      }
      dot[tc] = ah + al * (1.f / 2048.f);
    }

    // ---- phase 3 (no barrier: own-stripe writes only): yn -> sYa/sYb ----
#pragma unroll
    for (int tc = 0; tc < 4; ++tc) {
      const int C = 16 * tc + lr;
#pragma unroll
      for (int r_ = 0; r_ < 4; ++r_) {
        float yn = fmaxf(dot[tc][r_], 0.f);
        _Float16 th, tl;
        split16(yn, th, tl);
        sYa[R0 + r_][C] = th;
        sYb[R0 + r_][C] = tl;
      }
    }
    __syncthreads();

    // ---- phase 4: coalesced Y store; Zt from regs+LDS ----
#pragma unroll
    for (int q = 0; q < 4; ++q) {
      int fi = (q * NT + tid) * 4;
      int r = fi >> 6, c = fi & 63;
      h4 hh = *(const h4*)&sYa[r][c];
      h4 ll = *(const h4*)&sYb[r][c];
      float yn4[4];
#pragma unroll
      for (int j = 0; j < 4; ++j)
        yn4[j] = (float)hh[j] + (float)ll[j] * (1.f / 2048.f);
      *(float4*)(yo + fi) = make_float4(yn4[0], yn4[1], yn4[2], yn4[3]);
      if (!last) {
#pragma unroll
        for (int j = 0; j < 4; ++j) {
          float z = fmaf(0.9f, yn4[j], 0.1f * (&xv[q].x)[j]);
          _Float16 th, tl;
          split16(z, th, tl);
          sZa[c + j][r] = th;     // transposed scalar stores (<=4-way)
          sZb[c + j][r] = tl;
        }
      }
    }
    __syncthreads();

    // ---- phase 5: gram += Z^T Z (b64 frag reads, conflict-free) ----
    if (!last) {
      h8 ga_h[2], ga_l[2];
#pragma unroll
      for (int kh = 0; kh < 2; ++kh) {
        ga_h[kh] = ld_h8_2x(&sZa[16 * wv + lr][8 * lq + 32 * kh]);
        ga_l[kh] = ld_h8_2x(&sZb[16 * wv + lr][8 * lq + 32 * kh]);
      }
#pragma unroll
      for (int tc = 0; tc < 4; ++tc) {
        f32x4 lt = (f32x4){0.f, 0.f, 0.f, 0.f};
#pragma unroll
        for (int kh = 0; kh < 2; ++kh) {
          h8 gb_h = ld_h8_2x(&sZa[16 * tc + lr][8 * lq + 32 * kh]);
          h8 gb_l = ld_h8_2x(&sZb[16 * tc + lr][8 * lq + 32 * kh]);
          gacc[tc] = MFMA16x32(ga_h[kh], gb_h, gacc[tc]);
          lt = MFMA16x32(ga_h[kh], gb_l, lt);
          lt = MFMA16x32(ga_l[kh], gb_h, lt);
        }
        glo[tc] += lt;
      }
    }
    // no trailing barrier: next writes to sZ are 2 barriers away;
    // next writes to sYa (phase 1') race-free via phase-3' barrier path.
  }

  if (!last) {
    // partials store: G symmetric -> store transposed tile (64B/row groups)
    float* p = partials + (size_t)blk * NK * NK;
#pragma unroll
    for (int tc = 0; tc < 4; ++tc) {
      const int C = 16 * tc + lr;
      float4 g = make_float4(gacc[tc][0] + glo[tc][0] * (1.f / 2048.f),
                             gacc[tc][1] + glo[tc][1] * (1.f / 2048.f),
                             gacc[tc][2] + glo[tc][2] * (1.f / 2048.f),
                             gacc[tc][3] + glo[tc][3] * (1.f / 2048.f));
      *(float4*)(p + C * NK + R0) = g;
    }
  }
}

// ---------------------------------------------------------------------------
extern "C" void kernel_launch(void* const* d_in, const int* in_sizes, int n_in,
                              void* d_out, int out_size, void* d_ws,
                              size_t ws_size, hipStream_t stream) {
  (void)in_sizes; (void)n_in; (void)out_size;
  const float* X0 = (const float*)d_in[0];
  float* Y = (float*)d_out;

  const size_t slotf = (size_t)NK * NK;  // 4096
  const size_t need5 = ((size_t)(BATCH << 5)) * slotf * 4   // partials 16.8MB
                       + 2 * (size_t)BATCH * slotf * 2;     // S2 hi/lo 0.5MB
  const int shift = (ws_size >= need5) ? 5 : 4;
  const int nblk = BATCH << shift;

  float* partials = (float*)d_ws;
  _Float16* S2h = (_Float16*)((char*)d_ws + (size_t)nblk * slotf * 4);
  _Float16* S2l = S2h + (size_t)BATCH * slotf;

  k_init<<<nblk, NT, 0, stream>>>(X0, Y, partials, shift);
  for (int t = 0; t < NITER; ++t) {
    k_ns<<<BATCH, NT, 0, stream>>>(partials, S2h, S2l, 1 << shift);
    k_fused<<<nblk, NT, 0, stream>>>(X0, Y, S2h, S2l, partials,
                                     t == NITER - 1 ? 1 : 0, shift);
  }
}